// Round 1
// baseline (461.418 us; speedup 1.0000x reference)
//
#include <hip/hip_runtime.h>
#include <stdint.h>

#define SLEN 2048
#define DMODEL 1024
#define NHEADS 16
#define MTOT 8192   // 4 * 2048

typedef short s16x8 __attribute__((ext_vector_type(8)));
typedef short s16x4 __attribute__((ext_vector_type(4)));
typedef float f32x4 __attribute__((ext_vector_type(4)));

static __device__ __forceinline__ unsigned short f2bf(float f) {
  unsigned u = __builtin_bit_cast(unsigned, f);
  u += 0x7fffu + ((u >> 16) & 1u);           // RNE
  return (unsigned short)(u >> 16);
}

static __device__ __forceinline__ void gload_lds16(const void* g, void* l) {
  __builtin_amdgcn_global_load_lds((__attribute__((address_space(1))) void*)g,
                                   (__attribute__((address_space(3))) void*)l,
                                   16, 0, 0);
}

// ---------------- RoPE cos/sin table: [2048][32] each ----------------
__global__ void __launch_bounds__(256) rope_table(const int* __restrict__ pos,
                                                  float* __restrict__ ctab,
                                                  float* __restrict__ stab) {
  int g = blockIdx.x * 256 + threadIdx.x;     // 65536 total
  int s = g >> 5, i = g & 31;
  float p = (float)pos[s];
  // inv_freq[i] = 10000^(-2i/64) = 2^(-i * log2(10000)/32)
  float ang = p * exp2f(-(float)i * 0.41524101186092029f);
  ctab[g] = cosf(ang);
  stab[g] = sinf(ang);
}

// ---------------- fp32 -> bf16 convert (x4 vectorized) ----------------
__global__ void __launch_bounds__(256) cvt_f32_bf16(const float* __restrict__ src,
                                                    unsigned short* __restrict__ dst,
                                                    int n4) {
  int i = blockIdx.x * 256 + threadIdx.x;
  if (i >= n4) return;
  f32x4 v = ((const f32x4*)src)[i];
  s16x4 o;
#pragma unroll
  for (int j = 0; j < 4; ++j) o[j] = (short)f2bf(v[j]);
  ((s16x4*)dst)[i] = o;
}

// ---------------- GEMM: C[M=8192][N=1024] = A[M][K] * B[N][K]^T --------------
// MODE 0: store f32 row-major (final Wo projection)
// MODE 1: RoPE epilogue, scale, store bf16 to [bh][s][64]   (Q and K)
// MODE 2: store bf16 transposed V^T [bh][d][s]              (V)
template<int MODE>
__global__ void __launch_bounds__(256) gemm_nt(const unsigned short* __restrict__ A,
                                               const unsigned short* __restrict__ B,
                                               void* __restrict__ dstv,
                                               const float* __restrict__ ctab,
                                               const float* __restrict__ stab,
                                               float scale) {
  __shared__ unsigned short ldsA[2][128 * 32];
  __shared__ unsigned short ldsB[2][128 * 32];
  const int tid = threadIdx.x;
  const int lane = tid & 63;
  const int wave = tid >> 6;
  const int wm = wave >> 1, wn = wave & 1;
  const int m0 = blockIdx.y * 128;
  const int n0 = blockIdx.x * 128;
  const int l15 = lane & 15, lhi = lane >> 4;

  f32x4 acc[4][4] = {};

  // stage one 128x32 bf16 tile of A and B into LDS (16B chunks, XOR-swizzled
  // at the global source so LDS stays linear for global_load_lds).
  auto stage = [&](int buf, int kt) {
    const int kbase = kt * 32;
#pragma unroll
    for (int issue = 0; issue < 2; ++issue) {
      int c = issue * 256 + wave * 64 + lane;   // chunk id 0..511
      int row = c >> 2, kc = c & 3;
      int kcg = kc ^ ((row >> 1) & 3);          // source chunk for this slot
      gload_lds16(A + (size_t)(m0 + row) * 1024 + kbase + kcg * 8,
                  &ldsA[buf][(issue * 256 + wave * 64) * 8]);
      gload_lds16(B + (size_t)(n0 + row) * 1024 + kbase + kcg * 8,
                  &ldsB[buf][(issue * 256 + wave * 64) * 8]);
    }
  };

  stage(0, 0);
  for (int kt = 0; kt < 32; ++kt) {
    __syncthreads();
    if (kt + 1 < 32) stage((kt + 1) & 1, kt + 1);
    const int buf = kt & 1;
    s16x8 af[4], bf[4];
#pragma unroll
    for (int mi = 0; mi < 4; ++mi) {
      int row = wm * 64 + mi * 16 + l15;
      int kc = lhi ^ ((row >> 1) & 3);
      af[mi] = *(const s16x8*)&ldsA[buf][row * 32 + kc * 8];
    }
#pragma unroll
    for (int ni = 0; ni < 4; ++ni) {
      int row = wn * 64 + ni * 16 + l15;
      int kc = lhi ^ ((row >> 1) & 3);
      bf[ni] = *(const s16x8*)&ldsB[buf][row * 32 + kc * 8];
    }
#pragma unroll
    for (int mi = 0; mi < 4; ++mi)
#pragma unroll
      for (int ni = 0; ni < 4; ++ni)
        acc[mi][ni] = __builtin_amdgcn_mfma_f32_16x16x32_bf16(af[mi], bf[ni],
                                                              acc[mi][ni], 0, 0, 0);
  }

  // ---------------- epilogue ----------------
  // C layout (m89-verified): col = lane&15, row = (lane>>4)*4 + i
  if constexpr (MODE == 0) {
    float* dst = (float*)dstv;
#pragma unroll
    for (int mi = 0; mi < 4; ++mi)
#pragma unroll
      for (int ni = 0; ni < 4; ++ni)
#pragma unroll
        for (int i = 0; i < 4; ++i) {
          int r = m0 + wm * 64 + mi * 16 + lhi * 4 + i;
          int n = n0 + wn * 64 + ni * 16 + l15;
          dst[(size_t)r * 1024 + n] = acc[mi][ni][i];
        }
  } else if constexpr (MODE == 1) {
    unsigned short* dst = (unsigned short*)dstv;
#pragma unroll
    for (int mi = 0; mi < 4; ++mi)
#pragma unroll
      for (int ni = 0; ni < 4; ++ni)
#pragma unroll
        for (int i = 0; i < 4; ++i) {
          int r = m0 + wm * 64 + mi * 16 + lhi * 4 + i;
          int n = n0 + wn * 64 + ni * 16 + l15;
          float v = acc[mi][ni][i];
          float p = __shfl_xor(v, 1);           // RoPE partner (d+-1 = lane+-1)
          int s = r & (SLEN - 1);
          int d = n & 63;
          int fi = d >> 1;
          float c = ctab[s * 32 + fi], sn = stab[s * 32 + fi];
          float o = (d & 1) ? (p * sn + v * c) : (v * c - p * sn);
          o *= scale;
          int b = r >> 11, h = n >> 6;
          dst[((size_t)(b * NHEADS + h) * SLEN + s) * 64 + d] = f2bf(o);
        }
  } else {  // MODE 2: V^T [bh][d][s]
    unsigned short* dst = (unsigned short*)dstv;
#pragma unroll
    for (int mi = 0; mi < 4; ++mi)
#pragma unroll
      for (int ni = 0; ni < 4; ++ni) {
        int r0 = m0 + wm * 64 + mi * 16 + lhi * 4;   // 4 consecutive s
        int n = n0 + wn * 64 + ni * 16 + l15;
        int b = r0 >> 11, s0 = r0 & (SLEN - 1);
        int h = n >> 6, d = n & 63;
        s16x4 pk;
#pragma unroll
        for (int i = 0; i < 4; ++i) pk[i] = (short)f2bf(acc[mi][ni][i]);
        *(s16x4*)&dst[((size_t)(b * NHEADS + h) * 64 + d) * SLEN + s0] = pk;
      }
  }
}

// ---------------- causal flash attention ----------------
// Q,K: [bh][s][64] bf16 (Q pre-scaled by 0.125*log2e), Vt: [bh][64][s] bf16
// out: [b][s][h*64+d] bf16.  4 independent waves/block, 32 q-rows/wave.
// Swapped QK^T: S^T = mfma(K, Q) so softmax per q is a column reduce.
__global__ void __launch_bounds__(256) flash_attn(const unsigned short* __restrict__ Q,
                                                  const unsigned short* __restrict__ K,
                                                  const unsigned short* __restrict__ Vt,
                                                  unsigned short* __restrict__ Obf) {
  __shared__ unsigned short P_lds[4][32 * 64];   // per-wave P tile, 16B-granule XOR swizzle
  const int tid = threadIdx.x, lane = tid & 63, w = tid >> 6;
  const int l15 = lane & 15, lhi = lane >> 4;
  const int bh = blockIdx.y;
  const int qbase = blockIdx.x * 128 + w * 32;
  const unsigned short* Qb = Q + (size_t)bh * SLEN * 64;
  const unsigned short* Kb = K + (size_t)bh * SLEN * 64;
  const unsigned short* Vb = Vt + (size_t)bh * 64 * SLEN;

  // Q B-fragments, held in registers for the whole kernel
  s16x8 qf[2][2];
#pragma unroll
  for (int nq = 0; nq < 2; ++nq)
#pragma unroll
    for (int kd = 0; kd < 2; ++kd)
      qf[nq][kd] = *(const s16x8*)&Qb[(size_t)(qbase + nq * 16 + l15) * 64 + kd * 32 + lhi * 8];

  f32x4 acc_o[2][4] = {};
  float m_run[2] = {-1e30f, -1e30f};
  float l_run[2] = {0.f, 0.f};

  const int ktmax = (qbase + 31) >> 6;
  for (int kt = 0; kt <= ktmax; ++kt) {
    const int k0 = kt * 64;
    // S^T = K * Q^T  (A = K rows, B = Q rows; both k-contiguous)
    f32x4 sacc[4][2] = {};
#pragma unroll
    for (int mk = 0; mk < 4; ++mk) {
      s16x8 kf0 = *(const s16x8*)&Kb[(size_t)(k0 + mk * 16 + l15) * 64 + lhi * 8];
      s16x8 kf1 = *(const s16x8*)&Kb[(size_t)(k0 + mk * 16 + l15) * 64 + 32 + lhi * 8];
#pragma unroll
      for (int nq = 0; nq < 2; ++nq) {
        sacc[mk][nq] = __builtin_amdgcn_mfma_f32_16x16x32_bf16(kf0, qf[nq][0], sacc[mk][nq], 0, 0, 0);
        sacc[mk][nq] = __builtin_amdgcn_mfma_f32_16x16x32_bf16(kf1, qf[nq][1], sacc[mk][nq], 0, 0, 0);
      }
    }
    const bool needMask = (k0 + 63) > qbase;

    // online softmax (exp2 domain; scale folded into Q)
    float fac[2];
#pragma unroll
    for (int nq = 0; nq < 2; ++nq) {
      int qabs = qbase + nq * 16 + l15;
      float mx = -1e30f;
#pragma unroll
      for (int mk = 0; mk < 4; ++mk)
#pragma unroll
        for (int i = 0; i < 4; ++i) {
          int kabs = k0 + mk * 16 + lhi * 4 + i;
          float v = sacc[mk][nq][i];
          if (needMask && kabs > qabs) { v = -1e30f; sacc[mk][nq][i] = v; }
          mx = fmaxf(mx, v);
        }
      mx = fmaxf(mx, __shfl_xor(mx, 16));
      mx = fmaxf(mx, __shfl_xor(mx, 32));
      float mnew = fmaxf(m_run[nq], mx);
      fac[nq] = exp2f(m_run[nq] - mnew);
      m_run[nq] = mnew;
      float sum = 0.f;
#pragma unroll
      for (int mk = 0; mk < 4; ++mk) {
        f32x4 p;
#pragma unroll
        for (int i = 0; i < 4; ++i) { p[i] = exp2f(sacc[mk][nq][i] - mnew); sum += p[i]; }
        sacc[mk][nq] = p;
      }
      sum += __shfl_xor(sum, 16);
      sum += __shfl_xor(sum, 32);
      l_run[nq] = l_run[nq] * fac[nq] + sum;
    }

    // P -> bf16 -> LDS [32 q][64 k], XOR-swizzled 16B granules (conflict-free)
#pragma unroll
    for (int nq = 0; nq < 2; ++nq)
#pragma unroll
      for (int mk = 0; mk < 4; ++mk) {
        int q = nq * 16 + l15;
        int kloc = mk * 16 + lhi * 4;
        int kog = kloc >> 3, sub = (kloc >> 2) & 1;
        int off = q * 64 + ((kog ^ (q & 7)) * 8) + sub * 4;
        s16x4 pk;
#pragma unroll
        for (int i = 0; i < 4; ++i) pk[i] = (short)f2bf(sacc[mk][nq][i]);
        *(s16x4*)&P_lds[w][off] = pk;
      }

    // rescale running output (broadcast per-row factors)
#pragma unroll
    for (int mo = 0; mo < 2; ++mo) {
      f32x4 fr;
#pragma unroll
      for (int i = 0; i < 4; ++i) fr[i] = __shfl(fac[mo], lhi * 4 + i);
#pragma unroll
      for (int nd = 0; nd < 4; ++nd)
#pragma unroll
        for (int i = 0; i < 4; ++i) acc_o[mo][nd][i] *= fr[i];
    }

    // PV: A = P (from LDS), B = V^T rows (global, k-contiguous)
#pragma unroll
    for (int ks = 0; ks < 2; ++ks) {
      s16x8 pa[2];
#pragma unroll
      for (int mo = 0; mo < 2; ++mo) {
        int q = mo * 16 + l15;
        int kog = ks * 4 + lhi;
        pa[mo] = *(const s16x8*)&P_lds[w][q * 64 + ((kog ^ (q & 7)) * 8)];
      }
#pragma unroll
      for (int nd = 0; nd < 4; ++nd) {
        s16x8 vf = *(const s16x8*)&Vb[(size_t)(nd * 16 + l15) * SLEN + k0 + ks * 32 + lhi * 8];
#pragma unroll
        for (int mo = 0; mo < 2; ++mo)
          acc_o[mo][nd] = __builtin_amdgcn_mfma_f32_16x16x32_bf16(pa[mo], vf, acc_o[mo][nd], 0, 0, 0);
      }
    }
  }

  // normalize and store to [b][s][h*64+d]
  const int b = bh >> 4, h = bh & 15;
#pragma unroll
  for (int mo = 0; mo < 2; ++mo) {
    f32x4 lr;
#pragma unroll
    for (int i = 0; i < 4; ++i) lr[i] = __shfl(l_run[mo], lhi * 4 + i);
#pragma unroll
    for (int nd = 0; nd < 4; ++nd) {
      int d = nd * 16 + l15;
#pragma unroll
      for (int i = 0; i < 4; ++i) {
        int q = qbase + mo * 16 + lhi * 4 + i;
        float v = acc_o[mo][nd][i] / lr[i];
        Obf[((size_t)(b * SLEN + q)) * DMODEL + h * 64 + d] = f2bf(v);
      }
    }
  }
}

extern "C" void kernel_launch(void* const* d_in, const int* in_sizes, int n_in,
                              void* d_out, int out_size, void* d_ws, size_t ws_size,
                              hipStream_t stream) {
  const float* x  = (const float*)d_in[0];
  const float* Wq = (const float*)d_in[1];
  const float* Wk = (const float*)d_in[2];
  const float* Wv = (const float*)d_in[3];
  const float* Wo = (const float*)d_in[4];
  const int* pos  = (const int*)d_in[5];
  float* out = (float*)d_out;

  char* ws = (char*)d_ws;
  size_t off = 0;
  auto take = [&](size_t bytes) {
    char* p = ws + off;
    off += (bytes + 255) & ~(size_t)255;
    return p;
  };
  unsigned short* xbf  = (unsigned short*)take((size_t)MTOT * DMODEL * 2);
  unsigned short* wqbf = (unsigned short*)take((size_t)DMODEL * DMODEL * 2);
  unsigned short* wkbf = (unsigned short*)take((size_t)DMODEL * DMODEL * 2);
  unsigned short* wvbf = (unsigned short*)take((size_t)DMODEL * DMODEL * 2);
  unsigned short* wobf = (unsigned short*)take((size_t)DMODEL * DMODEL * 2);
  unsigned short* Qs   = (unsigned short*)take((size_t)64 * SLEN * 64 * 2);
  unsigned short* Ks   = (unsigned short*)take((size_t)64 * SLEN * 64 * 2);
  unsigned short* Vt   = (unsigned short*)take((size_t)64 * 64 * SLEN * 2);
  unsigned short* Obf  = (unsigned short*)take((size_t)MTOT * DMODEL * 2);
  float* ctab = (float*)take((size_t)SLEN * 32 * 4);
  float* stab = (float*)take((size_t)SLEN * 32 * 4);

  rope_table<<<256, 256, 0, stream>>>(pos, ctab, stab);
  cvt_f32_bf16<<<(MTOT * DMODEL / 4) / 256, 256, 0, stream>>>(x, xbf, MTOT * DMODEL / 4);
  cvt_f32_bf16<<<(DMODEL * DMODEL / 4) / 256, 256, 0, stream>>>(Wq, wqbf, DMODEL * DMODEL / 4);
  cvt_f32_bf16<<<(DMODEL * DMODEL / 4) / 256, 256, 0, stream>>>(Wk, wkbf, DMODEL * DMODEL / 4);
  cvt_f32_bf16<<<(DMODEL * DMODEL / 4) / 256, 256, 0, stream>>>(Wv, wvbf, DMODEL * DMODEL / 4);
  cvt_f32_bf16<<<(DMODEL * DMODEL / 4) / 256, 256, 0, stream>>>(Wo, wobf, DMODEL * DMODEL / 4);

  dim3 gg(DMODEL / 128, MTOT / 128);  // (8, 64)
  // Q: RoPE + fold softmax scale 0.125 * log2(e)
  gemm_nt<1><<<gg, 256, 0, stream>>>(xbf, wqbf, Qs, ctab, stab, 0.18033688011112042f);
  // K: RoPE only
  gemm_nt<1><<<gg, 256, 0, stream>>>(xbf, wkbf, Ks, ctab, stab, 1.0f);
  // V: transposed store
  gemm_nt<2><<<gg, 256, 0, stream>>>(xbf, wvbf, Vt, ctab, stab, 1.0f);

  flash_attn<<<dim3(SLEN / 128, 64), 256, 0, stream>>>(Qs, Ks, Vt, Obf);

  // final projection, fp32 output
  gemm_nt<0><<<gg, 256, 0, stream>>>(Obf, wobf, out, nullptr, nullptr, 1.0f);
}

// Round 2
// 315.678 us; speedup vs baseline: 1.4617x; 1.4617x over previous
//
#include <hip/hip_runtime.h>
#include <stdint.h>

#define SLEN 2048
#define DMODEL 1024
#define NHEADS 16
#define MTOT 8192   // 4 * 2048

typedef short s16x8 __attribute__((ext_vector_type(8)));
typedef short s16x4 __attribute__((ext_vector_type(4)));
typedef float f32x4 __attribute__((ext_vector_type(4)));
typedef unsigned u32x2 __attribute__((ext_vector_type(2)));

static __device__ __forceinline__ unsigned short f2bf(float f) {
  unsigned u = __builtin_bit_cast(unsigned, f);
  u += 0x7fffu + ((u >> 16) & 1u);           // RNE
  return (unsigned short)(u >> 16);
}

static __device__ __forceinline__ unsigned cvt_pk_bf16(float lo, float hi) {
  unsigned r;
  asm("v_cvt_pk_bf16_f32 %0, %1, %2" : "=v"(r) : "v"(lo), "v"(hi));
  return r;
}

static __device__ __forceinline__ void gload_lds16(const void* g, void* l) {
  __builtin_amdgcn_global_load_lds((__attribute__((address_space(1))) void*)g,
                                   (__attribute__((address_space(3))) void*)l,
                                   16, 0, 0);
}

// ---------------- RoPE cos/sin table: [2048][32] each ----------------
__global__ void __launch_bounds__(256) rope_table(const int* __restrict__ pos,
                                                  float* __restrict__ ctab,
                                                  float* __restrict__ stab) {
  int g = blockIdx.x * 256 + threadIdx.x;     // 65536 total
  int s = g >> 5, i = g & 31;
  float p = (float)pos[s];
  float ang = p * exp2f(-(float)i * 0.41524101186092029f);
  ctab[g] = cosf(ang);
  stab[g] = sinf(ang);
}

// ---------------- fp32 -> bf16 convert (x8 vectorized) ----------------
__global__ void __launch_bounds__(256) cvt_f32_bf16(const float* __restrict__ src,
                                                    unsigned short* __restrict__ dst,
                                                    int n8) {
  int i = blockIdx.x * 256 + threadIdx.x;
  if (i >= n8) return;
  f32x4 a = ((const f32x4*)src)[i * 2];
  f32x4 b = ((const f32x4*)src)[i * 2 + 1];
  s16x8 o;
#pragma unroll
  for (int j = 0; j < 4; ++j) o[j] = (short)f2bf(a[j]);
#pragma unroll
  for (int j = 0; j < 4; ++j) o[4 + j] = (short)f2bf(b[j]);
  ((s16x8*)dst)[i] = o;
}

// ---------------- GEMM: C[M=8192][N=1024] = A[M][K] * B[N][K]^T --------------
// MODE 0: store f32 row-major (final Wo projection)
// MODE 1: RoPE epilogue, scale, store bf16 to [bh][s][64]   (Q and K)
// MODE 2: store bf16 transposed V^T [bh][d][s]              (V)
template<int MODE>
__global__ void __launch_bounds__(256) gemm_nt(const unsigned short* __restrict__ A,
                                               const unsigned short* __restrict__ B,
                                               void* __restrict__ dstv,
                                               const float* __restrict__ ctab,
                                               const float* __restrict__ stab,
                                               float scale) {
  __shared__ unsigned short ldsA[2][128 * 32];
  __shared__ unsigned short ldsB[2][128 * 32];
  const int tid = threadIdx.x;
  const int lane = tid & 63;
  const int wave = tid >> 6;
  const int wm = wave >> 1, wn = wave & 1;
  const int m0 = blockIdx.y * 128;
  const int n0 = blockIdx.x * 128;
  const int l15 = lane & 15, lhi = lane >> 4;

  f32x4 acc[4][4] = {};

  auto stage = [&](int buf, int kt) {
    const int kbase = kt * 32;
#pragma unroll
    for (int issue = 0; issue < 2; ++issue) {
      int c = issue * 256 + wave * 64 + lane;   // chunk id 0..511
      int row = c >> 2, kc = c & 3;
      int kcg = kc ^ ((row >> 1) & 3);          // source chunk for this slot
      gload_lds16(A + (size_t)(m0 + row) * 1024 + kbase + kcg * 8,
                  &ldsA[buf][(issue * 256 + wave * 64) * 8]);
      gload_lds16(B + (size_t)(n0 + row) * 1024 + kbase + kcg * 8,
                  &ldsB[buf][(issue * 256 + wave * 64) * 8]);
    }
  };

  stage(0, 0);
  for (int kt = 0; kt < 32; ++kt) {
    __syncthreads();
    if (kt + 1 < 32) stage((kt + 1) & 1, kt + 1);
    const int buf = kt & 1;
    s16x8 af[4], bf[4];
#pragma unroll
    for (int mi = 0; mi < 4; ++mi) {
      int row = wm * 64 + mi * 16 + l15;
      int kc = lhi ^ ((row >> 1) & 3);
      af[mi] = *(const s16x8*)&ldsA[buf][row * 32 + kc * 8];
    }
#pragma unroll
    for (int ni = 0; ni < 4; ++ni) {
      int row = wn * 64 + ni * 16 + l15;
      int kc = lhi ^ ((row >> 1) & 3);
      bf[ni] = *(const s16x8*)&ldsB[buf][row * 32 + kc * 8];
    }
#pragma unroll
    for (int mi = 0; mi < 4; ++mi)
#pragma unroll
      for (int ni = 0; ni < 4; ++ni)
        acc[mi][ni] = __builtin_amdgcn_mfma_f32_16x16x32_bf16(af[mi], bf[ni],
                                                              acc[mi][ni], 0, 0, 0);
  }

  // C layout: col = lane&15, row = (lane>>4)*4 + i
  if constexpr (MODE == 0) {
    float* dst = (float*)dstv;
#pragma unroll
    for (int mi = 0; mi < 4; ++mi)
#pragma unroll
      for (int ni = 0; ni < 4; ++ni)
#pragma unroll
        for (int i = 0; i < 4; ++i) {
          int r = m0 + wm * 64 + mi * 16 + lhi * 4 + i;
          int n = n0 + wn * 64 + ni * 16 + l15;
          dst[(size_t)r * 1024 + n] = acc[mi][ni][i];
        }
  } else if constexpr (MODE == 1) {
    unsigned short* dst = (unsigned short*)dstv;
#pragma unroll
    for (int mi = 0; mi < 4; ++mi)
#pragma unroll
      for (int ni = 0; ni < 4; ++ni)
#pragma unroll
        for (int i = 0; i < 4; ++i) {
          int r = m0 + wm * 64 + mi * 16 + lhi * 4 + i;
          int n = n0 + wn * 64 + ni * 16 + l15;
          float v = acc[mi][ni][i];
          float p = __shfl_xor(v, 1);           // RoPE partner
          int s = r & (SLEN - 1);
          int d = n & 63;
          int fi = d >> 1;
          float c = ctab[s * 32 + fi], sn = stab[s * 32 + fi];
          float o = (d & 1) ? (p * sn + v * c) : (v * c - p * sn);
          o *= scale;
          int b = r >> 11, h = n >> 6;
          dst[((size_t)(b * NHEADS + h) * SLEN + s) * 64 + d] = f2bf(o);
        }
  } else {  // MODE 2: V^T [bh][d][s]
    unsigned short* dst = (unsigned short*)dstv;
#pragma unroll
    for (int mi = 0; mi < 4; ++mi)
#pragma unroll
      for (int ni = 0; ni < 4; ++ni) {
        int r0 = m0 + wm * 64 + mi * 16 + lhi * 4;
        int n = n0 + wn * 64 + ni * 16 + l15;
        int b = r0 >> 11, s0 = r0 & (SLEN - 1);
        int h = n >> 6, d = n & 63;
        s16x4 pk;
#pragma unroll
        for (int i = 0; i < 4; ++i) pk[i] = (short)f2bf(acc[mi][ni][i]);
        *(s16x4*)&dst[((size_t)(b * NHEADS + h) * 64 + d) * SLEN + s0] = pk;
      }
  }
}

// ---------------- causal flash attention, v2 ----------------
// Q,K: [bh][s][64] bf16 (Q pre-scaled by 0.125*log2e), Vt: [bh][64][s] bf16
// out: [b][s][h*64+d] bf16.
// Block = 128 threads = 2 waves. Block handles q-tile PAIR (t, 63-t), 32 rows
// each -> uniform 33 k-tiles per pair (zero tail). Within a tile the 2 waves
// split k-tiles by parity (flash split-k), merged in LDS at tile end.
// S^T = mfma(K, Q); O^T = mfma(Vt, P^T) -> rescale + normalize lane-local.
__global__ void __launch_bounds__(128, 3) flash_attn(const unsigned short* __restrict__ Q,
                                                     const unsigned short* __restrict__ K,
                                                     const unsigned short* __restrict__ Vt,
                                                     unsigned short* __restrict__ Obf) {
  __shared__ unsigned short P_lds[2][32 * 64];  // per-wave P tile, XOR-swizzled 16B granules
  __shared__ float M_acc[32 * 68];              // merge buffer O^T (stride 68 kills conflicts)
  __shared__ float M_m[32], M_l[32];

  const int tid = threadIdx.x, lane = tid & 63, w = tid >> 6;   // w = k-parity
  const int l15 = lane & 15, lhi = lane >> 4;

  // XCD-chunked swizzle: 2048 blocks, 8 XCDs -> XCD k gets bh in [k*8, k*8+8)
  int id = blockIdx.x;
  int logical = (id & 7) * 256 + (id >> 3);
  const int bh = logical >> 5, tpair = logical & 31;
  const int b = bh >> 4, h = bh & 15;

  const unsigned short* Qb = Q + (size_t)bh * SLEN * 64;
  const unsigned short* Kb = K + (size_t)bh * SLEN * 64;
  const unsigned short* Vb = Vt + (size_t)bh * 64 * SLEN;

  for (int half = 0; half < 2; ++half) {
    const int t = (half == 0) ? tpair : 63 - tpair;
    const int qbase = t * 32;
    const int nt = (qbase >> 6) + 1;            // k-tiles incl. diagonal

    // Q B-fragments for this tile (held in regs)
    s16x8 qf[2][2];
#pragma unroll
    for (int nq = 0; nq < 2; ++nq)
#pragma unroll
      for (int kd = 0; kd < 2; ++kd)
        qf[nq][kd] = *(const s16x8*)&Qb[(size_t)(qbase + nq * 16 + l15) * 64 + kd * 32 + lhi * 8];

    f32x4 accT[4][2] = {};                      // O^T: row d = md*16+lhi*4+i, col q = nq*16+l15
    float m_run[2] = {-3.0e38f, -3.0e38f};
    float l_run[2] = {0.f, 0.f};

    for (int kt = w; kt < nt; kt += 2) {
      const int k0 = kt * 64;
      const bool diag = (kt == nt - 1);

      // K A-fragments (8 batched 16B loads)
      s16x8 kf[4][2];
#pragma unroll
      for (int mk = 0; mk < 4; ++mk) {
        const unsigned short* kr = &Kb[(size_t)(k0 + mk * 16 + l15) * 64 + lhi * 8];
        kf[mk][0] = *(const s16x8*)kr;
        kf[mk][1] = *(const s16x8*)(kr + 32);
      }

      // S^T = K * Q^T
      f32x4 sacc[4][2] = {};
#pragma unroll
      for (int mk = 0; mk < 4; ++mk)
#pragma unroll
        for (int nq = 0; nq < 2; ++nq) {
          sacc[mk][nq] = __builtin_amdgcn_mfma_f32_16x16x32_bf16(kf[mk][0], qf[nq][0], sacc[mk][nq], 0, 0, 0);
          sacc[mk][nq] = __builtin_amdgcn_mfma_f32_16x16x32_bf16(kf[mk][1], qf[nq][1], sacc[mk][nq], 0, 0, 0);
        }

      // prefetch V (ks=0) while softmax runs
      s16x8 vf0[4];
#pragma unroll
      for (int md = 0; md < 4; ++md)
        vf0[md] = *(const s16x8*)&Vb[(size_t)(md * 16 + l15) * SLEN + k0 + lhi * 8];

      // online softmax (exp2 domain); mask only on the diagonal tile
      float fac[2];
#pragma unroll
      for (int nq = 0; nq < 2; ++nq) {
        const int qabs = qbase + nq * 16 + l15;
        if (diag) {
#pragma unroll
          for (int mk = 0; mk < 4; ++mk)
#pragma unroll
            for (int i = 0; i < 4; ++i) {
              int kabs = k0 + mk * 16 + lhi * 4 + i;
              if (kabs > qabs) sacc[mk][nq][i] = -3.0e38f;
            }
        }
        float mx = sacc[0][nq][0];
#pragma unroll
        for (int mk = 0; mk < 4; ++mk)
#pragma unroll
          for (int i = 0; i < 4; ++i) mx = fmaxf(mx, sacc[mk][nq][i]);
        mx = fmaxf(mx, __shfl_xor(mx, 16));
        mx = fmaxf(mx, __shfl_xor(mx, 32));
        const float mnew = fmaxf(m_run[nq], mx);
        fac[nq] = exp2f(m_run[nq] - mnew);
        m_run[nq] = mnew;
        float s0 = 0.f, s1 = 0.f;
#pragma unroll
        for (int mk = 0; mk < 4; ++mk) {
          f32x4 p;
#pragma unroll
          for (int i = 0; i < 4; ++i) p[i] = exp2f(sacc[mk][nq][i] - mnew);
          s0 += p[0] + p[1];
          s1 += p[2] + p[3];
          sacc[mk][nq] = p;
        }
        float sum = s0 + s1;
        sum += __shfl_xor(sum, 16);
        sum += __shfl_xor(sum, 32);
        l_run[nq] = l_run[nq] * fac[nq] + sum;
        // rescale running O^T columns: lane-local (col q = l15)
#pragma unroll
        for (int md = 0; md < 4; ++md)
#pragma unroll
          for (int i = 0; i < 4; ++i) accT[md][nq][i] *= fac[nq];
      }

      // P -> bf16 -> LDS [32 q][64 k], XOR-swizzled 16B granules
#pragma unroll
      for (int nq = 0; nq < 2; ++nq)
#pragma unroll
        for (int mk = 0; mk < 4; ++mk) {
          int q = nq * 16 + l15;
          int kloc = mk * 16 + lhi * 4;
          int kog = kloc >> 3, sub = (kloc >> 2) & 1;
          int off = q * 64 + ((kog ^ (q & 7)) * 8) + sub * 4;
          u32x2 pk;
          pk[0] = cvt_pk_bf16(sacc[mk][nq][0], sacc[mk][nq][1]);
          pk[1] = cvt_pk_bf16(sacc[mk][nq][2], sacc[mk][nq][3]);
          *(u32x2*)&P_lds[w][off] = pk;
        }

      // PV: O^T += Vt_frag (A) * P^T (B)
#pragma unroll
      for (int ks = 0; ks < 2; ++ks) {
        s16x8 vf[4];
        if (ks == 0) {
#pragma unroll
          for (int md = 0; md < 4; ++md) vf[md] = vf0[md];
        } else {
#pragma unroll
          for (int md = 0; md < 4; ++md)
            vf[md] = *(const s16x8*)&Vb[(size_t)(md * 16 + l15) * SLEN + k0 + 32 + lhi * 8];
        }
        s16x8 pa[2];
#pragma unroll
        for (int nq = 0; nq < 2; ++nq) {
          int q = nq * 16 + l15;
          int kog = ks * 4 + lhi;
          pa[nq] = *(const s16x8*)&P_lds[w][q * 64 + ((kog ^ (q & 7)) * 8)];
        }
#pragma unroll
        for (int md = 0; md < 4; ++md)
#pragma unroll
          for (int nq = 0; nq < 2; ++nq)
            accT[md][nq] = __builtin_amdgcn_mfma_f32_16x16x32_bf16(vf[md], pa[nq], accT[md][nq], 0, 0, 0);
      }
    }

    // ---- merge the two k-parity partials, then store (wave 0) ----
    if (w == 1) {
#pragma unroll
      for (int nq = 0; nq < 2; ++nq) {
        int q = nq * 16 + l15;
        M_m[q] = m_run[nq];
        M_l[q] = l_run[nq];
#pragma unroll
        for (int md = 0; md < 4; ++md)
          *(f32x4*)&M_acc[q * 68 + md * 16 + lhi * 4] = accT[md][nq];
      }
    }
    __syncthreads();
    if (w == 0) {
#pragma unroll
      for (int nq = 0; nq < 2; ++nq) {
        int q = nq * 16 + l15;
        float mB = M_m[q], lB = M_l[q];
        float m = fmaxf(m_run[nq], mB);
        float fa = exp2f(m_run[nq] - m);
        float fb = exp2f(mB - m);
        float linv = 1.f / (l_run[nq] * fa + lB * fb);
#pragma unroll
        for (int md = 0; md < 4; ++md) {
          f32x4 ob = *(const f32x4*)&M_acc[q * 68 + md * 16 + lhi * 4];
          float v0 = (accT[md][nq][0] * fa + ob[0] * fb) * linv;
          float v1 = (accT[md][nq][1] * fa + ob[1] * fb) * linv;
          float v2 = (accT[md][nq][2] * fa + ob[2] * fb) * linv;
          float v3 = (accT[md][nq][3] * fa + ob[3] * fb) * linv;
          u32x2 pk;
          pk[0] = cvt_pk_bf16(v0, v1);
          pk[1] = cvt_pk_bf16(v2, v3);
          *(u32x2*)&Obf[((size_t)(b * SLEN + qbase + q)) * DMODEL + h * 64 + md * 16 + lhi * 4] = pk;
        }
      }
    }
    __syncthreads();
  }
}

extern "C" void kernel_launch(void* const* d_in, const int* in_sizes, int n_in,
                              void* d_out, int out_size, void* d_ws, size_t ws_size,
                              hipStream_t stream) {
  const float* x  = (const float*)d_in[0];
  const float* Wq = (const float*)d_in[1];
  const float* Wk = (const float*)d_in[2];
  const float* Wv = (const float*)d_in[3];
  const float* Wo = (const float*)d_in[4];
  const int* pos  = (const int*)d_in[5];
  float* out = (float*)d_out;

  char* ws = (char*)d_ws;
  size_t off = 0;
  auto take = [&](size_t bytes) {
    char* p = ws + off;
    off += (bytes + 255) & ~(size_t)255;
    return p;
  };
  unsigned short* xbf  = (unsigned short*)take((size_t)MTOT * DMODEL * 2);
  unsigned short* wqbf = (unsigned short*)take((size_t)DMODEL * DMODEL * 2);
  unsigned short* wkbf = (unsigned short*)take((size_t)DMODEL * DMODEL * 2);
  unsigned short* wvbf = (unsigned short*)take((size_t)DMODEL * DMODEL * 2);
  unsigned short* wobf = (unsigned short*)take((size_t)DMODEL * DMODEL * 2);
  unsigned short* Qs   = (unsigned short*)take((size_t)64 * SLEN * 64 * 2);
  unsigned short* Ks   = (unsigned short*)take((size_t)64 * SLEN * 64 * 2);
  unsigned short* Vt   = (unsigned short*)take((size_t)64 * 64 * SLEN * 2);
  unsigned short* Obf  = (unsigned short*)take((size_t)MTOT * DMODEL * 2);
  float* ctab = (float*)take((size_t)SLEN * 32 * 4);
  float* stab = (float*)take((size_t)SLEN * 32 * 4);

  rope_table<<<256, 256, 0, stream>>>(pos, ctab, stab);
  cvt_f32_bf16<<<(MTOT * DMODEL / 8) / 256, 256, 0, stream>>>(x, xbf, MTOT * DMODEL / 8);
  cvt_f32_bf16<<<(DMODEL * DMODEL / 8) / 256, 256, 0, stream>>>(Wq, wqbf, DMODEL * DMODEL / 8);
  cvt_f32_bf16<<<(DMODEL * DMODEL / 8) / 256, 256, 0, stream>>>(Wk, wkbf, DMODEL * DMODEL / 8);
  cvt_f32_bf16<<<(DMODEL * DMODEL / 8) / 256, 256, 0, stream>>>(Wv, wvbf, DMODEL * DMODEL / 8);
  cvt_f32_bf16<<<(DMODEL * DMODEL / 8) / 256, 256, 0, stream>>>(Wo, wobf, DMODEL * DMODEL / 8);

  dim3 gg(DMODEL / 128, MTOT / 128);  // (8, 64)
  // Q: RoPE + fold softmax scale 0.125 * log2(e)
  gemm_nt<1><<<gg, 256, 0, stream>>>(xbf, wqbf, Qs, ctab, stab, 0.18033688011112042f);
  // K: RoPE only
  gemm_nt<1><<<gg, 256, 0, stream>>>(xbf, wkbf, Ks, ctab, stab, 1.0f);
  // V: transposed store
  gemm_nt<2><<<gg, 256, 0, stream>>>(xbf, wvbf, Vt, ctab, stab, 1.0f);

  flash_attn<<<2048, 128, 0, stream>>>(Qs, Ks, Vt, Obf);

  // final projection, fp32 output
  gemm_nt<0><<<gg, 256, 0, stream>>>(Obf, wobf, out, nullptr, nullptr, 1.0f);
}

// Round 3
// 242.900 us; speedup vs baseline: 1.8996x; 1.2996x over previous
//
#include <hip/hip_runtime.h>
#include <stdint.h>

#define SLEN 2048
#define DMODEL 1024
#define NHEADS 16
#define MTOT 8192   // 4 * 2048

typedef short s16x8 __attribute__((ext_vector_type(8)));
typedef short s16x4 __attribute__((ext_vector_type(4)));
typedef float f32x4 __attribute__((ext_vector_type(4)));
typedef unsigned u32x2 __attribute__((ext_vector_type(2)));

static __device__ __forceinline__ unsigned short f2bf(float f) {
  unsigned u = __builtin_bit_cast(unsigned, f);
  u += 0x7fffu + ((u >> 16) & 1u);           // RNE
  return (unsigned short)(u >> 16);
}

static __device__ __forceinline__ unsigned cvt_pk_bf16(float lo, float hi) {
  unsigned r;
  asm("v_cvt_pk_bf16_f32 %0, %1, %2" : "=v"(r) : "v"(lo), "v"(hi));
  return r;
}

static __device__ __forceinline__ void gload_lds16(const void* g, void* l) {
  __builtin_amdgcn_global_load_lds((__attribute__((address_space(1))) void*)g,
                                   (__attribute__((address_space(3))) void*)l,
                                   16, 0, 0);
}

#define MFMA16(a, b, c) __builtin_amdgcn_mfma_f32_16x16x32_bf16(a, b, c, 0, 0, 0)

// ---------------- RoPE cos/sin table: [2048][32] each ----------------
__global__ void __launch_bounds__(256) rope_table(const int* __restrict__ pos,
                                                  float* __restrict__ ctab,
                                                  float* __restrict__ stab) {
  int g = blockIdx.x * 256 + threadIdx.x;     // 65536 total
  int s = g >> 5, i = g & 31;
  float p = (float)pos[s];
  float ang = p * exp2f(-(float)i * 0.41524101186092029f);
  ctab[g] = cosf(ang);
  stab[g] = sinf(ang);
}

// ---------------- fp32 -> bf16 convert (x8 vectorized) ----------------
__global__ void __launch_bounds__(256) cvt_f32_bf16(const float* __restrict__ src,
                                                    unsigned short* __restrict__ dst,
                                                    int n8) {
  int i = blockIdx.x * 256 + threadIdx.x;
  if (i >= n8) return;
  f32x4 a = ((const f32x4*)src)[i * 2];
  f32x4 b = ((const f32x4*)src)[i * 2 + 1];
  s16x8 o;
#pragma unroll
  for (int j = 0; j < 4; ++j) o[j] = (short)f2bf(a[j]);
#pragma unroll
  for (int j = 0; j < 4; ++j) o[4 + j] = (short)f2bf(b[j]);
  ((s16x8*)dst)[i] = o;
}

// all four weight matrices in one dispatch (grid.y selects)
__global__ void __launch_bounds__(256) cvt_weights(const float* __restrict__ w0,
                                                   const float* __restrict__ w1,
                                                   const float* __restrict__ w2,
                                                   const float* __restrict__ w3,
                                                   unsigned short* __restrict__ d0,
                                                   unsigned short* __restrict__ d1,
                                                   unsigned short* __restrict__ d2,
                                                   unsigned short* __restrict__ d3) {
  int which = blockIdx.y;
  const float* src = which == 0 ? w0 : which == 1 ? w1 : which == 2 ? w2 : w3;
  unsigned short* dst = which == 0 ? d0 : which == 1 ? d1 : which == 2 ? d2 : d3;
  int i = blockIdx.x * 256 + threadIdx.x;     // 131072 per matrix
  f32x4 a = ((const f32x4*)src)[i * 2];
  f32x4 b = ((const f32x4*)src)[i * 2 + 1];
  s16x8 o;
#pragma unroll
  for (int j = 0; j < 4; ++j) o[j] = (short)f2bf(a[j]);
#pragma unroll
  for (int j = 0; j < 4; ++j) o[4 + j] = (short)f2bf(b[j]);
  ((s16x8*)dst)[i] = o;
}

// ---------------- GEMM: C[M=8192][N=1024] = A[M][K] * B[N][K]^T --------------
// MODE 0: store f32 row-major (final Wo projection)
// MODE 1: RoPE epilogue, scale, store bf16 to [bh][s][64]   (Q and K)
// MODE 2: store bf16 transposed V^T [bh][d][s]              (V)
template<int MODE>
__global__ void __launch_bounds__(256) gemm_nt(const unsigned short* __restrict__ A,
                                               const unsigned short* __restrict__ B,
                                               void* __restrict__ dstv,
                                               const float* __restrict__ ctab,
                                               const float* __restrict__ stab,
                                               float scale) {
  __shared__ unsigned short ldsA[2][128 * 32];
  __shared__ unsigned short ldsB[2][128 * 32];
  const int tid = threadIdx.x;
  const int lane = tid & 63;
  const int wave = tid >> 6;
  const int wm = wave >> 1, wn = wave & 1;
  const int m0 = blockIdx.y * 128;
  const int n0 = blockIdx.x * 128;
  const int l15 = lane & 15, lhi = lane >> 4;

  f32x4 acc[4][4] = {};

  auto stage = [&](int buf, int kt) {
    const int kbase = kt * 32;
#pragma unroll
    for (int issue = 0; issue < 2; ++issue) {
      int c = issue * 256 + wave * 64 + lane;   // chunk id 0..511
      int row = c >> 2, kc = c & 3;
      int kcg = kc ^ ((row >> 1) & 3);          // source chunk for this slot
      gload_lds16(A + (size_t)(m0 + row) * 1024 + kbase + kcg * 8,
                  &ldsA[buf][(issue * 256 + wave * 64) * 8]);
      gload_lds16(B + (size_t)(n0 + row) * 1024 + kbase + kcg * 8,
                  &ldsB[buf][(issue * 256 + wave * 64) * 8]);
    }
  };

  stage(0, 0);
  for (int kt = 0; kt < 32; ++kt) {
    __syncthreads();
    if (kt + 1 < 32) stage((kt + 1) & 1, kt + 1);
    const int buf = kt & 1;
    s16x8 af[4], bf[4];
#pragma unroll
    for (int mi = 0; mi < 4; ++mi) {
      int row = wm * 64 + mi * 16 + l15;
      int kc = lhi ^ ((row >> 1) & 3);
      af[mi] = *(const s16x8*)&ldsA[buf][row * 32 + kc * 8];
    }
#pragma unroll
    for (int ni = 0; ni < 4; ++ni) {
      int row = wn * 64 + ni * 16 + l15;
      int kc = lhi ^ ((row >> 1) & 3);
      bf[ni] = *(const s16x8*)&ldsB[buf][row * 32 + kc * 8];
    }
#pragma unroll
    for (int mi = 0; mi < 4; ++mi)
#pragma unroll
      for (int ni = 0; ni < 4; ++ni)
        acc[mi][ni] = MFMA16(af[mi], bf[ni], acc[mi][ni]);
  }

  // C layout: col = lane&15, row = (lane>>4)*4 + i
  if constexpr (MODE == 0) {
    float* dst = (float*)dstv;
#pragma unroll
    for (int mi = 0; mi < 4; ++mi)
#pragma unroll
      for (int ni = 0; ni < 4; ++ni)
#pragma unroll
        for (int i = 0; i < 4; ++i) {
          int r = m0 + wm * 64 + mi * 16 + lhi * 4 + i;
          int n = n0 + wn * 64 + ni * 16 + l15;
          dst[(size_t)r * 1024 + n] = acc[mi][ni][i];
        }
  } else if constexpr (MODE == 1) {
    unsigned short* dst = (unsigned short*)dstv;
#pragma unroll
    for (int mi = 0; mi < 4; ++mi)
#pragma unroll
      for (int ni = 0; ni < 4; ++ni)
#pragma unroll
        for (int i = 0; i < 4; ++i) {
          int r = m0 + wm * 64 + mi * 16 + lhi * 4 + i;
          int n = n0 + wn * 64 + ni * 16 + l15;
          float v = acc[mi][ni][i];
          float p = __shfl_xor(v, 1);           // RoPE partner
          int s = r & (SLEN - 1);
          int d = n & 63;
          int fi = d >> 1;
          float c = ctab[s * 32 + fi], sn = stab[s * 32 + fi];
          float o = (d & 1) ? (p * sn + v * c) : (v * c - p * sn);
          o *= scale;
          int b = r >> 11, h = n >> 6;
          dst[((size_t)(b * NHEADS + h) * SLEN + s) * 64 + d] = f2bf(o);
        }
  } else {  // MODE 2: V^T [bh][d][s]
    unsigned short* dst = (unsigned short*)dstv;
#pragma unroll
    for (int mi = 0; mi < 4; ++mi)
#pragma unroll
      for (int ni = 0; ni < 4; ++ni) {
        int r0 = m0 + wm * 64 + mi * 16 + lhi * 4;
        int n = n0 + wn * 64 + ni * 16 + l15;
        int b = r0 >> 11, s0 = r0 & (SLEN - 1);
        int h = n >> 6, d = n & 63;
        s16x4 pk;
#pragma unroll
        for (int i = 0; i < 4; ++i) pk[i] = (short)f2bf(acc[mi][ni][i]);
        *(s16x4*)&dst[((size_t)(b * NHEADS + h) * 64 + d) * SLEN + s0] = pk;
      }
  }
}

// ---------------- causal flash attention, v3 ----------------
// Q,K: [bh][s][64] bf16 (Q pre-scaled by 0.125*log2e), Vt: [bh][64][s] bf16.
// Block = 128 threads (2 waves). Block handles q-tile PAIR (t, 31-t) of 64
// rows -> uniform 33 k-tiles. Each wave owns 32 q-cols for ALL k-tiles
// (no cross-wave merge). K tile staged to LDS via global_load_lds
// (double-buffered, source-swizzled, one __syncthreads per tile = the
// vmcnt drain). V read direct from global (L2-resident). P via private LDS.
__global__ void __launch_bounds__(128, 2) flash_attn(const unsigned short* __restrict__ Q,
                                                     const unsigned short* __restrict__ K,
                                                     const unsigned short* __restrict__ Vt,
                                                     unsigned short* __restrict__ Obf) {
  __shared__ unsigned short Kbuf[2][64 * 64];   // 16 KB, 16B-granule swizzle ^(row&7)
  __shared__ unsigned short Pbuf[2][32 * 64];   // 8 KB, per-wave private

  const int tid = threadIdx.x, lane = tid & 63, w = tid >> 6;
  const int l15 = lane & 15, lhi = lane >> 4;
  const int swz = l15 & 7;

  // XCD-chunked swizzle: XCD k gets bh in [8k, 8k+8)
  int id = blockIdx.x;                          // 1024 blocks
  int logical = (id & 7) * 128 + (id >> 3);
  const int bh = logical >> 4;                  // 0..63
  const int tp = logical & 15;                  // pair id 0..15
  const int b = bh >> 4, h = bh & 15;

  const unsigned short* Qb = Q + (size_t)bh * SLEN * 64;
  const unsigned short* Kb = K + (size_t)bh * SLEN * 64;
  const unsigned short* Vb = Vt + (size_t)bh * 64 * SLEN;

  // stage one 64x64 K tile; source pre-swizzled so LDS reads are conflict-free
  auto stageK = [&](int buf, int k0) {
#pragma unroll
    for (int j = 0; j < 4; ++j) {
      int c = j * 128 + tid;                    // 16B chunk 0..511
      int row = c >> 3, cg = c & 7;
      gload_lds16(Kb + (size_t)(k0 + row) * 64 + ((cg ^ (row & 7)) * 8),
                  &Kbuf[buf][c * 8]);
    }
  };

  for (int half = 0; half < 2; ++half) {
    const int t = half ? (31 - tp) : tp;
    const int qbase = t * 64;
    const int nt = t + 1;

    // Q B-fragments: wave w owns q-cols [w*32, w*32+32)
    s16x8 qf[2][2];
#pragma unroll
    for (int nq = 0; nq < 2; ++nq)
#pragma unroll
      for (int kd = 0; kd < 2; ++kd)
        qf[nq][kd] = *(const s16x8*)&Qb[(size_t)(qbase + w * 32 + nq * 16 + l15) * 64 + kd * 32 + lhi * 8];

    f32x4 accT[4][2] = {};                      // O^T: row d, col q (lane-local q = l15 slot)
    float m_run[2] = {-3.0e38f, -3.0e38f};
    float l_run[2] = {0.f, 0.f};

    stageK(0, 0);
    for (int kt = 0; kt < nt; ++kt) {
      const int cur = kt & 1;
      const int k0 = kt * 64;
      __syncthreads();                          // drains vmcnt: prev stage landed; all waves done with other buf
      if (kt + 1 < nt) stageK(cur ^ 1, (kt + 1) * 64);

      // prefetch V ks=0 fragments early (hidden under QK^T + softmax)
      s16x8 vf0[4];
#pragma unroll
      for (int md = 0; md < 4; ++md)
        vf0[md] = *(const s16x8*)&Vb[(size_t)(md * 16 + l15) * SLEN + k0 + lhi * 8];

      // K A-fragments from LDS (swizzled)
      s16x8 kf[4][2];
#pragma unroll
      for (int mk = 0; mk < 4; ++mk) {
        int r = mk * 16 + l15;
#pragma unroll
        for (int kd = 0; kd < 2; ++kd)
          kf[mk][kd] = *(const s16x8*)&Kbuf[cur][r * 64 + (((kd * 4 + lhi) ^ swz) * 8)];
      }

      // S^T = K * Q^T
      f32x4 sacc[4][2] = {};
#pragma unroll
      for (int mk = 0; mk < 4; ++mk)
#pragma unroll
        for (int nq = 0; nq < 2; ++nq) {
          sacc[mk][nq] = MFMA16(kf[mk][0], qf[nq][0], sacc[mk][nq]);
          sacc[mk][nq] = MFMA16(kf[mk][1], qf[nq][1], sacc[mk][nq]);
        }

      const bool diag = (kt == nt - 1);
      float fac[2];
#pragma unroll
      for (int nq = 0; nq < 2; ++nq) {
        const int qloc = w * 32 + nq * 16 + l15;
        if (diag) {
#pragma unroll
          for (int mk = 0; mk < 4; ++mk)
#pragma unroll
            for (int i = 0; i < 4; ++i)
              if (mk * 16 + lhi * 4 + i > qloc) sacc[mk][nq][i] = -3.0e38f;
        }
        float mx = sacc[0][nq][0];
#pragma unroll
        for (int mk = 0; mk < 4; ++mk)
#pragma unroll
          for (int i = 0; i < 4; ++i) mx = fmaxf(mx, sacc[mk][nq][i]);
        mx = fmaxf(mx, __shfl_xor(mx, 16));
        mx = fmaxf(mx, __shfl_xor(mx, 32));
        const float mnew = fmaxf(m_run[nq], mx);
        fac[nq] = exp2f(m_run[nq] - mnew);
        m_run[nq] = mnew;
        float s0 = 0.f, s1 = 0.f;
#pragma unroll
        for (int mk = 0; mk < 4; ++mk) {
          f32x4 p;
#pragma unroll
          for (int i = 0; i < 4; ++i) p[i] = exp2f(sacc[mk][nq][i] - mnew);
          s0 += p[0] + p[1];
          s1 += p[2] + p[3];
          sacc[mk][nq] = p;
        }
        float sum = s0 + s1;
        sum += __shfl_xor(sum, 16);
        sum += __shfl_xor(sum, 32);
        l_run[nq] = l_run[nq] * fac[nq] + sum;
#pragma unroll
        for (int md = 0; md < 4; ++md)
#pragma unroll
          for (int i = 0; i < 4; ++i) accT[md][nq][i] *= fac[nq];
      }

      // P -> bf16 -> private LDS [32 q][64 k], 16B-granule swizzle ^(q&7)
#pragma unroll
      for (int nq = 0; nq < 2; ++nq)
#pragma unroll
        for (int mk = 0; mk < 4; ++mk) {
          int q = nq * 16 + l15;
          int kog = mk * 2 + (lhi >> 1);
          int off = q * 64 + ((kog ^ swz) * 8) + (lhi & 1) * 4;
          u32x2 pk;
          pk[0] = cvt_pk_bf16(sacc[mk][nq][0], sacc[mk][nq][1]);
          pk[1] = cvt_pk_bf16(sacc[mk][nq][2], sacc[mk][nq][3]);
          *(u32x2*)&Pbuf[w][off] = pk;
        }

      // PV: O^T += Vt_frag (A) * P^T (B)
#pragma unroll
      for (int ks = 0; ks < 2; ++ks) {
        s16x8 pa[2];
#pragma unroll
        for (int nq = 0; nq < 2; ++nq) {
          int q = nq * 16 + l15;
          pa[nq] = *(const s16x8*)&Pbuf[w][q * 64 + (((ks * 4 + lhi) ^ swz) * 8)];
        }
        s16x8 vv[4];
        if (ks == 0) {
#pragma unroll
          for (int md = 0; md < 4; ++md) vv[md] = vf0[md];
        } else {
#pragma unroll
          for (int md = 0; md < 4; ++md)
            vv[md] = *(const s16x8*)&Vb[(size_t)(md * 16 + l15) * SLEN + k0 + 32 + lhi * 8];
        }
#pragma unroll
        for (int md = 0; md < 4; ++md)
#pragma unroll
          for (int nq = 0; nq < 2; ++nq)
            accT[md][nq] = MFMA16(vv[md], pa[nq], accT[md][nq]);
      }
    }

    // normalize (lane-local) and store O^T -> [b][s][h*64+d]
#pragma unroll
    for (int nq = 0; nq < 2; ++nq) {
      float linv = 1.f / l_run[nq];
      int qg = qbase + w * 32 + nq * 16 + l15;
#pragma unroll
      for (int md = 0; md < 4; ++md) {
        u32x2 pk;
        pk[0] = cvt_pk_bf16(accT[md][nq][0] * linv, accT[md][nq][1] * linv);
        pk[1] = cvt_pk_bf16(accT[md][nq][2] * linv, accT[md][nq][3] * linv);
        *(u32x2*)&Obf[((size_t)(b * SLEN + qg)) * DMODEL + h * 64 + md * 16 + lhi * 4] = pk;
      }
    }
    __syncthreads();   // protect Kbuf before next half's prologue stage
  }
}

extern "C" void kernel_launch(void* const* d_in, const int* in_sizes, int n_in,
                              void* d_out, int out_size, void* d_ws, size_t ws_size,
                              hipStream_t stream) {
  const float* x  = (const float*)d_in[0];
  const float* Wq = (const float*)d_in[1];
  const float* Wk = (const float*)d_in[2];
  const float* Wv = (const float*)d_in[3];
  const float* Wo = (const float*)d_in[4];
  const int* pos  = (const int*)d_in[5];
  float* out = (float*)d_out;

  char* ws = (char*)d_ws;
  size_t off = 0;
  auto take = [&](size_t bytes) {
    char* p = ws + off;
    off += (bytes + 255) & ~(size_t)255;
    return p;
  };
  unsigned short* xbf  = (unsigned short*)take((size_t)MTOT * DMODEL * 2);
  unsigned short* wqbf = (unsigned short*)take((size_t)DMODEL * DMODEL * 2);
  unsigned short* wkbf = (unsigned short*)take((size_t)DMODEL * DMODEL * 2);
  unsigned short* wvbf = (unsigned short*)take((size_t)DMODEL * DMODEL * 2);
  unsigned short* wobf = (unsigned short*)take((size_t)DMODEL * DMODEL * 2);
  unsigned short* Qs   = (unsigned short*)take((size_t)64 * SLEN * 64 * 2);
  unsigned short* Ks   = (unsigned short*)take((size_t)64 * SLEN * 64 * 2);
  unsigned short* Vt   = (unsigned short*)take((size_t)64 * 64 * SLEN * 2);
  unsigned short* Obf  = (unsigned short*)take((size_t)MTOT * DMODEL * 2);
  float* ctab = (float*)take((size_t)SLEN * 32 * 4);
  float* stab = (float*)take((size_t)SLEN * 32 * 4);

  rope_table<<<256, 256, 0, stream>>>(pos, ctab, stab);
  cvt_f32_bf16<<<4096, 256, 0, stream>>>(x, xbf, MTOT * DMODEL / 8);
  cvt_weights<<<dim3(512, 4), 256, 0, stream>>>(Wq, Wk, Wv, Wo, wqbf, wkbf, wvbf, wobf);

  dim3 gg(DMODEL / 128, MTOT / 128);  // (8, 64)
  // Q: RoPE + fold softmax scale 0.125 * log2(e)
  gemm_nt<1><<<gg, 256, 0, stream>>>(xbf, wqbf, Qs, ctab, stab, 0.18033688011112042f);
  // K: RoPE only
  gemm_nt<1><<<gg, 256, 0, stream>>>(xbf, wkbf, Ks, ctab, stab, 1.0f);
  // V: transposed store
  gemm_nt<2><<<gg, 256, 0, stream>>>(xbf, wvbf, Vt, ctab, stab, 1.0f);

  flash_attn<<<1024, 128, 0, stream>>>(Qs, Ks, Vt, Obf);

  // final projection, fp32 output
  gemm_nt<0><<<gg, 256, 0, stream>>>(Obf, wobf, out, nullptr, nullptr, 1.0f);
}